// Round 7
// baseline (3119.708 us; speedup 1.0000x reference)
//
#include <hip/hip_runtime.h>
#include <hip/hip_bf16.h>
#include <math.h>

// Problem constants
#define BB 16
#define LL 512
#define DD 512
#define DD2 1024
#define KMIX 8
#define LPAD 520          // L + 8 pad rows (4 each side) for KS=9 conv
#define GRU_KSTEPS 33     // Wp layout keeps 33 k-steps; scan uses 0..31 (bias via scalars)

typedef __attribute__((ext_vector_type(8))) short short8;
typedef __attribute__((ext_vector_type(4))) float f32x4;
typedef unsigned short ushort;

__device__ __forceinline__ float bf2f(ushort u) {
  union { float f; unsigned i; } v; v.i = ((unsigned)u) << 16; return v.f;
}
__device__ __forceinline__ ushort f2bf(float f) {
  union { float f; unsigned i; } v; v.f = f;
  unsigned i = v.i;
  unsigned r = i + 0x7FFF + ((i >> 16) & 1);   // RNE
  return (ushort)(r >> 16);
}

// ---------------------------------------------------------------------------
// Elementwise prep kernels (grid-stride)
// ---------------------------------------------------------------------------
__global__ void k_zero_bf16(ushort* p, long n) {
  for (long i = blockIdx.x * 256 + threadIdx.x; i < n; i += (long)gridDim.x * 256) p[i] = 0;
}
// xpad[b][p][d] = p in [4,516) ? bf16(x[b][p-4][d]) : 0
__global__ void k_fill_xpad(const float* __restrict__ x, ushort* __restrict__ xp) {
  const long n = (long)BB * LPAD * DD;
  for (long i = blockIdx.x * 256 + threadIdx.x; i < n; i += (long)gridDim.x * 256) {
    int d = (int)(i & 511);
    long rest = i >> 9;
    int p = (int)(rest % LPAD);
    int b = (int)(rest / LPAD);
    float v = 0.f;
    if (p >= 4 && p < 516) v = x[((long)b * LL + (p - 4)) * DD + d];
    xp[i] = f2bf(v);
  }
}
// wpack[k][o][i] = w[o][i][k]  (conv weight -> per-segment B^T layout [N=o][K=i])
__global__ void k_pack_convw(const float* __restrict__ w, ushort* __restrict__ wp) {
  const long n = (long)DD * DD * 9;
  for (long idx = blockIdx.x * 256 + threadIdx.x; idx < n; idx += (long)gridDim.x * 256) {
    int i = (int)(idx & 511);
    int o = (int)((idx >> 9) & 511);
    int k = (int)(idx >> 18);
    wp[idx] = f2bf(w[((long)o * DD + i) * 9 + k]);
  }
}
// wihx[n][i] = w_ih[n][i], n<3072, i<512 (x-part of w_ih, B^T layout)
__global__ void k_pack_wihx(const float* __restrict__ w_ih, ushort* __restrict__ wp) {
  const long n = (long)3 * DD2 * DD;
  for (long idx = blockIdx.x * 256 + threadIdx.x; idx < n; idx += (long)gridDim.x * 256) {
    int i = (int)(idx & 511);
    int nr = (int)(idx >> 9);
    wp[idx] = f2bf(w_ih[(long)nr * 1536 + i]);
  }
}
__global__ void k_pack_bf16(const float* __restrict__ s, ushort* __restrict__ d, long n) {
  for (long i = blockIdx.x * 256 + threadIdx.x; i < n; i += (long)gridDim.x * 256) d[i] = f2bf(s[i]);
}
// GRU weights in exact B-fragment order (layout unchanged; ks=32 unused in scan).
__global__ void k_pack_gru(const float* __restrict__ w_ih, const float* __restrict__ w_hh,
                           const float* __restrict__ b_hh, ushort* __restrict__ wp) {
  const long n = (long)64 * 6 * GRU_KSTEPS * 64 * 8;
  for (long idx = blockIdx.x * 256 + threadIdx.x; idx < n; idx += (long)gridDim.x * 256) {
    int j = (int)(idx & 7);
    int lane = (int)((idx >> 3) & 63);
    long r9 = idx >> 9;
    int ks = (int)(r9 % GRU_KSTEPS);
    long tmp = r9 / GRU_KSTEPS;
    int s = (int)(tmp % 6);
    int blk = (int)(tmp / 6);
    int k = ks * 32 + ((lane >> 4) << 3) + j;
    int u = blk * 16 + (lane & 15);
    float v = 0.f;
    if (s < 3) {
      if (k < 1024) v = w_ih[((long)(s * DD2 + u)) * 1536 + 512 + k];
    } else {
      int nr = (s - 3) * DD2 + u;
      if (k < 1024) v = w_hh[(long)nr * DD2 + k];
      else if (k == 1024) v = b_hh[nr];
    }
    wp[idx] = f2bf(v);
  }
}
// Zero hbuf[0] (h0 = 0, frag order) and the packed flag array.
__global__ void k_init_hbuf(ushort* hb, unsigned* flags) {
  int i = blockIdx.x * 256 + threadIdx.x;
  if (i < 16384) hb[i] = 0;
  if (i < 256) flags[i] = 0u;
}

// ---------------------------------------------------------------------------
// Generic 128x128 bf16 MFMA GEMM.
// MODE: 0 +bias->f32 ; 1 +bias->bf16 ; 2 +bias->f32 ; 3 exp(+bias)->f32 ;
//       4 +bias->bf16 in packed gix layout [t][ublock][slice][b][u_local]
// ---------------------------------------------------------------------------
template <int MODE, int AMAP>
__global__ __launch_bounds__(256) void gemm128(
    const ushort* __restrict__ A, int lda, long segAoff,
    const ushort* __restrict__ Bt, int ldb, long segBoff,
    int nseg, int kseg, void* __restrict__ Cout, int ldc,
    const float* __restrict__ bias) {
  __shared__ ushort As[128 * 64];
  __shared__ ushort Bs[128 * 64];
  const int tid = threadIdx.x, lane = tid & 63, w = tid >> 6;
  const int wr = w >> 1, wc = w & 1;
  const int m0 = blockIdx.y * 128, n0 = blockIdx.x * 128;

  const ushort* Abase;
  if (AMAP == 1) {
    int b = m0 >> 9, l = m0 & 511;
    Abase = A + ((long)(b * LPAD + l)) * DD;
  } else {
    Abase = A + (long)m0 * lda;
  }
  const ushort* Bbase = Bt + (long)n0 * ldb;

  f32x4 acc[4][4];
#pragma unroll
  for (int i = 0; i < 4; i++)
#pragma unroll
    for (int j = 0; j < 4; j++) acc[i][j] = {0.f, 0.f, 0.f, 0.f};

  for (int seg = 0; seg < nseg; ++seg) {
    const ushort* Aseg = Abase + (long)seg * segAoff;
    const ushort* Bseg = Bbase + (long)seg * segBoff;
    for (int k0 = 0; k0 < kseg; k0 += 64) {
#pragma unroll
      for (int it = 0; it < 4; ++it) {
        int chunk = it * 256 + tid;
        int r = chunk >> 3, cc = chunk & 7;
        int sc = cc ^ (r & 7);
        *(short8*)&As[(size_t)chunk * 8] = *(const short8*)(Aseg + (long)r * lda + k0 + sc * 8);
        *(short8*)&Bs[(size_t)chunk * 8] = *(const short8*)(Bseg + (long)r * ldb + k0 + sc * 8);
      }
      __syncthreads();
#pragma unroll
      for (int kk = 0; kk < 2; ++kk) {
        short8 af[4], bfv[4];
#pragma unroll
        for (int m = 0; m < 4; m++) {
          int row = wr * 64 + m * 16 + (lane & 15);
          int ch = (kk * 4 + (lane >> 4)) ^ (row & 7);
          af[m] = *(const short8*)&As[(size_t)(row * 8 + ch) * 8];
        }
#pragma unroll
        for (int nn = 0; nn < 4; nn++) {
          int row = wc * 64 + nn * 16 + (lane & 15);
          int ch = (kk * 4 + (lane >> 4)) ^ (row & 7);
          bfv[nn] = *(const short8*)&Bs[(size_t)(row * 8 + ch) * 8];
        }
#pragma unroll
        for (int m = 0; m < 4; m++)
#pragma unroll
          for (int nn = 0; nn < 4; nn++)
            acc[m][nn] = __builtin_amdgcn_mfma_f32_16x16x32_bf16(af[m], bfv[nn], acc[m][nn], 0, 0, 0);
      }
      __syncthreads();
    }
  }
  float bvals[4];
#pragma unroll
  for (int nn = 0; nn < 4; nn++) {
    int c = n0 + wc * 64 + nn * 16 + (lane & 15);
    bvals[nn] = bias[c];
  }
#pragma unroll
  for (int m = 0; m < 4; m++) {
    int rbase = m0 + wr * 64 + m * 16 + ((lane >> 4) << 2);
#pragma unroll
    for (int nn = 0; nn < 4; nn++) {
      int c = n0 + wc * 64 + nn * 16 + (lane & 15);
#pragma unroll
      for (int j = 0; j < 4; j++) {
        float v = acc[m][nn][j] + bvals[nn];
        long off = (long)(rbase + j) * ldc + c;
        if (MODE == 0) ((float*)Cout)[off] = v;
        else if (MODE == 1) ((ushort*)Cout)[off] = f2bf(v);
        else if (MODE == 2) ((float*)Cout)[off] = v;
        else if (MODE == 3) ((float*)Cout)[off] = expf(v);
        else {
          // MODE 4: packed gix for gru_scan. row=(b*512+t), col=(s*1024+u)
          int r = rbase + j;
          int bb = r >> 9, tt = r & 511, ss = c >> 10, uu = c & 1023;
          long o2 = ((((long)(tt * 64 + (uu >> 4))) * 3 + ss) << 8) + (bb << 4) + (uu & 15);
          ((ushort*)Cout)[o2] = f2bf(v);
        }
      }
    }
  }
}

// ---------------------------------------------------------------------------
// LayerNorm(D=512) + ReLU (unchanged).
// ---------------------------------------------------------------------------
template <int DSTPAD>
__global__ __launch_bounds__(256) void ln_relu(
    const float* __restrict__ y, const float* __restrict__ g,
    const float* __restrict__ be, ushort* __restrict__ dst) {
  const int r = blockIdx.x, tid = threadIdx.x;
  float v0 = y[(long)r * DD + tid];
  float v1 = y[(long)r * DD + 256 + tid];
  float s = v0 + v1, sq = v0 * v0 + v1 * v1;
#pragma unroll
  for (int o = 32; o; o >>= 1) { s += __shfl_down(s, o); sq += __shfl_down(sq, o); }
  __shared__ float red[8];
  int w = tid >> 6, lane = tid & 63;
  if (lane == 0) { red[w] = s; red[4 + w] = sq; }
  __syncthreads();
  if (tid == 0) {
    float ts = 0.f, tq = 0.f;
#pragma unroll
    for (int i = 0; i < 4; i++) { ts += red[i]; tq += red[4 + i]; }
    red[0] = ts; red[1] = tq;
  }
  __syncthreads();
  float mean = red[0] * (1.f / 512.f);
  float var = red[1] * (1.f / 512.f) - mean * mean;
  float rs = rsqrtf(var + 1e-5f);
  long dbase;
  if (DSTPAD) { int b = r >> 9, l = r & 511; dbase = ((long)(b * LPAD + l + 4)) * DD; }
  else dbase = (long)r * DD;
  float o0 = fmaxf(0.f, (v0 - mean) * rs * g[tid] + be[tid]);
  float o1 = fmaxf(0.f, (v1 - mean) * rs * g[tid + 256] + be[tid + 256]);
  dst[dbase + tid] = f2bf(o0);
  dst[dbase + 256 + tid] = f2bf(o1);
}

// ---------------------------------------------------------------------------
// Persistent GRU scan, v7 = v3's proven sync skeleton + packed flags +
// full weight register preload + packed gix.
//   arrive:  h stores (relaxed agent) + h_seq store; __syncthreads (drains
//            vmcnt for every wave); tid0 stores flags[blk]=t+1 (relaxed).
//   detect:  wave0 polls flags[lane] — 64 contiguous u32 = 4 cache lines,
//            coalesced into 4 line-requests per poll (v6 lesson: poll
//            footprint x pollers is what serializes at L3);
//            __syncthreads broadcast.
// All 6 weight slices live in registers (~192 VGPR; 64 blocks = 1/CU).
// gix is consumed from the packed [t][ublock][slice][b][u_local] layout —
// one contiguous 1536 B chunk per (block, step), nontemporal.
// ---------------------------------------------------------------------------
__global__ __launch_bounds__(256, 1) void gru_scan(
    const ushort* __restrict__ Wp, const ushort* __restrict__ gix2,
    const float* __restrict__ b_hh,
    ushort* __restrict__ hbuf, ushort* __restrict__ h_seq,
    unsigned* __restrict__ flags) {
  __shared__ float red[4 * 6 * 256];  // 24 KB
  const int tid = threadIdx.x, lane = tid & 63, w = tid >> 6, blk = blockIdx.x;
  const int j_c = w;                              // gate-phase j index = wave id
  const int u_local = lane & 15;
  const int b = ((lane >> 4) << 2) + j_c;         // gate-phase batch
  const int u = (blk << 4) + u_local;             // gate-phase unit
  // frag position of (u,b) in next step's A buffer: k=u
  const int lanep = ((blk & 1) * 2 + (u_local >> 3)) * 16 + b;
  const long hout_off = ((long)(blk >> 1) * 64 + lanep) * 8 + (u_local & 7);
  const ushort* wpw = Wp + (long)blk * 6 * GRU_KSTEPS * 512 + (long)lane * 8;
  const float bhr = b_hh[u], bhz = b_hh[DD2 + u], bhn = b_hh[2 * DD2 + u];
  float hold = 0.f;

  // Preload ALL 6 weight slices into registers (192 VGPRs of payload).
  short8 wr0[8], wr1[8], wr2[8], wr3[8], wr4[8], wr5[8];
#pragma unroll
  for (int i = 0; i < 8; ++i) {
    const int ks = i * 4 + w;
    wr0[i] = *(const short8*)(wpw + (long)(0 * GRU_KSTEPS + ks) * 512);
    wr1[i] = *(const short8*)(wpw + (long)(1 * GRU_KSTEPS + ks) * 512);
    wr2[i] = *(const short8*)(wpw + (long)(2 * GRU_KSTEPS + ks) * 512);
    wr3[i] = *(const short8*)(wpw + (long)(3 * GRU_KSTEPS + ks) * 512);
    wr4[i] = *(const short8*)(wpw + (long)(4 * GRU_KSTEPS + ks) * 512);
    wr5[i] = *(const short8*)(wpw + (long)(5 * GRU_KSTEPS + ks) * 512);
  }

  const int gofs = (b << 4) + u_local;
  for (int t = 0; t < LL; ++t) {
    // gate-input loads: one contiguous 1536B chunk per (blk,t); issued BEFORE
    // the poll so HBM latency overlaps the wait. Nontemporal (pure stream).
    const long gbase = ((long)(t * 64 + blk) * 3) << 8;
    const float gx_r = bf2f(__builtin_nontemporal_load(gix2 + gbase + gofs));
    const float gx_z = bf2f(__builtin_nontemporal_load(gix2 + gbase + 256 + gofs));
    const float gx_n = bf2f(__builtin_nontemporal_load(gix2 + gbase + 512 + gofs));

    // Detect: wave0 polls the 4-line packed flag array; syncthreads broadcast.
    if (t > 0) {
      if (w == 0) {
        const unsigned tgt = (unsigned)t;
        while (1) {
          unsigned f = __hip_atomic_load(&flags[lane], __ATOMIC_RELAXED,
                                         __HIP_MEMORY_SCOPE_AGENT);
          if (__all((int)(f >= tgt))) break;
          __builtin_amdgcn_s_sleep(2);
        }
      }
      __syncthreads();
    }

    const ushort* hb = hbuf + ((long)t << 14);
    f32x4 acc0 = {0.f,0.f,0.f,0.f}, acc1 = acc0, acc2 = acc0,
          acc3 = acc0, acc4 = acc0, acc5 = acc0;
#pragma unroll
    for (int i = 0; i < 8; ++i) {
      const int ks = i * 4 + w;
      unsigned long long* ap = (unsigned long long*)(hb + (((long)ks * 64 + lane) << 3));
      union { unsigned long long q[2]; short8 v; } cv;
      cv.q[0] = __hip_atomic_load(ap,     __ATOMIC_RELAXED, __HIP_MEMORY_SCOPE_AGENT);
      cv.q[1] = __hip_atomic_load(ap + 1, __ATOMIC_RELAXED, __HIP_MEMORY_SCOPE_AGENT);
      acc0 = __builtin_amdgcn_mfma_f32_16x16x32_bf16(cv.v, wr0[i], acc0, 0, 0, 0);
      acc1 = __builtin_amdgcn_mfma_f32_16x16x32_bf16(cv.v, wr1[i], acc1, 0, 0, 0);
      acc2 = __builtin_amdgcn_mfma_f32_16x16x32_bf16(cv.v, wr2[i], acc2, 0, 0, 0);
      acc3 = __builtin_amdgcn_mfma_f32_16x16x32_bf16(cv.v, wr3[i], acc3, 0, 0, 0);
      acc4 = __builtin_amdgcn_mfma_f32_16x16x32_bf16(cv.v, wr4[i], acc4, 0, 0, 0);
      acc5 = __builtin_amdgcn_mfma_f32_16x16x32_bf16(cv.v, wr5[i], acc5, 0, 0, 0);
    }
    // Cross-wave reduce, transposed layout (conflict-free both sides).
#pragma unroll
    for (int j = 0; j < 4; ++j) {
      red[((w * 6 + 0) << 8) + (j << 6) + lane] = acc0[j];
      red[((w * 6 + 1) << 8) + (j << 6) + lane] = acc1[j];
      red[((w * 6 + 2) << 8) + (j << 6) + lane] = acc2[j];
      red[((w * 6 + 3) << 8) + (j << 6) + lane] = acc3[j];
      red[((w * 6 + 4) << 8) + (j << 6) + lane] = acc4[j];
      red[((w * 6 + 5) << 8) + (j << 6) + lane] = acc5[j];
    }
    __syncthreads();
    float v0 = 0.f, v1 = 0.f, v2 = 0.f, v3 = 0.f, v4 = 0.f, v5 = 0.f;
#pragma unroll
    for (int wv = 0; wv < 4; ++wv) {
      const int base = ((wv * 6) << 8) + (j_c << 6) + lane;
      v0 += red[base];
      v1 += red[base + 256];
      v2 += red[base + 512];
      v3 += red[base + 768];
      v4 += red[base + 1024];
      v5 += red[base + 1280];
    }
    // gates (b_hh folded in as scalars; n-gate bias inside r*(.) per torch GRUCell)
    const float rg = 1.f / (1.f + __expf(-(gx_r + v0 + v3 + bhr)));
    const float zg = 1.f / (1.f + __expf(-(gx_z + v1 + v4 + bhz)));
    const float nx = gx_n + v2 + rg * (v5 + bhn);
    const float ng = 1.f - 2.f / (__expf(2.f * nx) + 1.f);
    const float hn = (1.f - zg) * ng + zg * hold;
    hold = hn;
    const ushort h16 = f2bf(hn);
    __builtin_nontemporal_store(h16, h_seq + ((long)b * LL + t) * DD2 + u);
    if (t < LL - 1) {
      // publish h (write-through to the coherence point, relaxed)
      __hip_atomic_store(hbuf + (((long)(t + 1)) << 14) + hout_off, h16,
                         __ATOMIC_RELAXED, __HIP_MEMORY_SCOPE_AGENT);
      __syncthreads();  // drains vmcnt(0) for every wave before the flag
      if (tid == 0)
        __hip_atomic_store(&flags[blk], (unsigned)(t + 1), __ATOMIC_RELAXED,
                           __HIP_MEMORY_SCOPE_AGENT);
    }
  }
}

// ---------------------------------------------------------------------------
// Mixture-weight head (unchanged).
// ---------------------------------------------------------------------------
__global__ __launch_bounds__(256) void w_head(
    const ushort* __restrict__ h_seq, const float* __restrict__ ww,
    const float* __restrict__ wb, float* __restrict__ out) {
  const int tid = threadIdx.x, lane = tid & 63, w = tid >> 6;
  const long r = (long)blockIdx.x * 4 + w;
  float s[KMIX];
#pragma unroll
  for (int k = 0; k < KMIX; k++) s[k] = 0.f;
  for (int u = lane; u < DD2; u += 64) {
    float hv = bf2f(h_seq[r * DD2 + u]);
#pragma unroll
    for (int k = 0; k < KMIX; k++) s[k] += hv * ww[(long)k * DD2 + u];
  }
#pragma unroll
  for (int k = 0; k < KMIX; k++)
#pragma unroll
    for (int o = 32; o; o >>= 1) s[k] += __shfl_xor(s[k], o);
#pragma unroll
  for (int k = 0; k < KMIX; k++) s[k] += wb[k];
  float m = s[0];
#pragma unroll
  for (int k = 1; k < KMIX; k++) m = fmaxf(m, s[k]);
  float esum = 0.f;
#pragma unroll
  for (int k = 0; k < KMIX; k++) { s[k] = expf(s[k] - m); esum += s[k]; }
  float mine = 0.f;
#pragma unroll
  for (int k = 0; k < KMIX; k++) if (lane == k) mine = s[k];
  if (lane < KMIX) out[r * KMIX + lane] = mine / esum;
}

// ---------------------------------------------------------------------------
extern "C" void kernel_launch(void* const* d_in, const int* in_sizes, int n_in,
                              void* d_out, int out_size, void* d_ws, size_t ws_size,
                              hipStream_t stream) {
  const float* h_text     = (const float*)d_in[0];
  const float* conv1_w    = (const float*)d_in[1];
  const float* conv1_b    = (const float*)d_in[2];
  const float* ln1_g      = (const float*)d_in[3];
  const float* ln1_b      = (const float*)d_in[4];
  const float* conv2_w    = (const float*)d_in[5];
  const float* conv2_b    = (const float*)d_in[6];
  const float* ln2_g      = (const float*)d_in[7];
  const float* ln2_b      = (const float*)d_in[8];
  const float* w_ih       = (const float*)d_in[9];
  const float* w_hh       = (const float*)d_in[10];
  const float* b_ih       = (const float*)d_in[11];
  const float* b_hh       = (const float*)d_in[12];
  const float* mdn_w_w    = (const float*)d_in[13];
  const float* mdn_w_b    = (const float*)d_in[14];
  const float* mdn_sig_w  = (const float*)d_in[15];
  const float* mdn_sig_b  = (const float*)d_in[16];
  const float* mdn_mu_w   = (const float*)d_in[17];
  const float* mdn_mu_b   = (const float*)d_in[18];
  float* out = (float*)d_out;

  char* ws = (char*)d_ws;
  size_t off = 0;
  auto take = [&](size_t bytes) {
    void* p = ws + off;
    off += (bytes + 255) & ~(size_t)255;
    return p;
  };
  ushort* xpad1  = (ushort*)take((size_t)BB * LPAD * DD * 2);
  ushort* xpad2  = (ushort*)take((size_t)BB * LPAD * DD * 2);
  ushort* wpack1 = (ushort*)take((size_t)DD * DD * 9 * 2);
  ushort* wpack2 = (ushort*)take((size_t)DD * DD * 9 * 2);
  float*  ybuf   = (float*) take((size_t)BB * LL * DD * 4);
  ushort* x2     = (ushort*)take((size_t)BB * LL * DD * 2);
  ushort* wihx   = (ushort*)take((size_t)3 * DD2 * DD * 2);
  ushort* gix    = (ushort*)take((size_t)BB * LL * 3 * DD2 * 2);   // packed layout
  ushort* Wp     = (ushort*)take((size_t)64 * 6 * GRU_KSTEPS * 64 * 8 * 2);
  ushort* hseq   = (ushort*)take((size_t)BB * LL * DD2 * 2);
  ushort* mdnmu  = (ushort*)take((size_t)KMIX * DD2 * DD2 * 2);
  ushort* mdnsg  = (ushort*)take((size_t)KMIX * DD2 * DD2 * 2);
  ushort* hbuf   = (ushort*)take((size_t)512 * 16384 * 2);   // 512 write-once frag buffers
  unsigned* flags = (unsigned*)take(256 * 4);                // 64 packed flags (4 lines)

  const long sigma_off = (long)BB * LL * KMIX;                    // 65536
  const long mu_off    = sigma_off + (long)BB * LL * KMIX * DD2;  // 67174400

  // --- prep / packing ---
  k_fill_xpad<<<2048, 256, 0, stream>>>(h_text, xpad1);
  k_zero_bf16<<<2048, 256, 0, stream>>>(xpad2, (long)BB * LPAD * DD);
  k_pack_convw<<<2048, 256, 0, stream>>>(conv1_w, wpack1);
  k_pack_convw<<<2048, 256, 0, stream>>>(conv2_w, wpack2);
  k_pack_wihx<<<2048, 256, 0, stream>>>(w_ih, wihx);
  k_pack_gru<<<2048, 256, 0, stream>>>(w_ih, w_hh, b_hh, Wp);
  k_pack_bf16<<<2048, 256, 0, stream>>>(mdn_mu_w, mdnmu, (long)KMIX * DD2 * DD2);
  k_pack_bf16<<<2048, 256, 0, stream>>>(mdn_sig_w, mdnsg, (long)KMIX * DD2 * DD2);
  k_init_hbuf<<<64, 256, 0, stream>>>(hbuf, flags);

  // --- conv block 1: y = conv(xpad1) + b ; LN+ReLU -> xpad2 ---
  gemm128<0, 1><<<dim3(4, 64), 256, 0, stream>>>(xpad1, DD, DD, wpack1, DD, (long)DD * DD, 9, DD,
                                                 ybuf, DD, conv1_b);
  ln_relu<1><<<BB * LL, 256, 0, stream>>>(ybuf, ln1_g, ln1_b, xpad2);

  // --- conv block 2 -> x2 (GRU input, plain bf16 [8192,512]) ---
  gemm128<0, 1><<<dim3(4, 64), 256, 0, stream>>>(xpad2, DD, DD, wpack2, DD, (long)DD * DD, 9, DD,
                                                 ybuf, DD, conv2_b);
  ln_relu<0><<<BB * LL, 256, 0, stream>>>(ybuf, ln2_g, ln2_b, x2);

  // --- gi_x = x2 @ w_ih[:, :512]^T + b_ih -> PACKED gix layout (MODE=4) ---
  gemm128<4, 0><<<dim3(24, 64), 256, 0, stream>>>(x2, DD, 0, wihx, DD, 0, 1, DD,
                                                  gix, 3 * DD2, b_ih);

  // --- persistent GRU scan (v3 skeleton, packed flags, reg-resident weights) ---
  gru_scan<<<64, 256, 0, stream>>>(Wp, gix, b_hh, hbuf, hseq, flags);

  // --- MDN heads ---
  gemm128<3, 0><<<dim3(64, 64), 256, 0, stream>>>(hseq, DD2, 0, mdnsg, DD2, 0, 1, DD2,
                                                  out + sigma_off, KMIX * DD2, mdn_sig_b);
  gemm128<2, 0><<<dim3(64, 64), 256, 0, stream>>>(hseq, DD2, 0, mdnmu, DD2, 0, 1, DD2,
                                                  out + mu_off, KMIX * DD2, mdn_mu_b);
  w_head<<<BB * LL / 4, 256, 0, stream>>>(hseq, mdn_w_w, mdn_w_b, out);
}

// Round 8
// 2673.008 us; speedup vs baseline: 1.1671x; 1.1671x over previous
//
#include <hip/hip_runtime.h>
#include <hip/hip_bf16.h>
#include <math.h>

// Problem constants
#define BB 16
#define LL 512
#define DD 512
#define DD2 1024
#define KMIX 8
#define LPAD 520          // L + 8 pad rows (4 each side) for KS=9 conv
#define GRU_KSTEPS 33     // Wp layout keeps 33 k-steps; scan uses 0..31 (bias via scalars)

typedef __attribute__((ext_vector_type(8))) short short8;
typedef __attribute__((ext_vector_type(4))) float f32x4;
typedef unsigned short ushort;

__device__ __forceinline__ float bf2f(ushort u) {
  union { float f; unsigned i; } v; v.i = ((unsigned)u) << 16; return v.f;
}
__device__ __forceinline__ ushort f2bf(float f) {
  union { float f; unsigned i; } v; v.f = f;
  unsigned i = v.i;
  unsigned r = i + 0x7FFF + ((i >> 16) & 1);   // RNE
  return (ushort)(r >> 16);
}

// ---------------------------------------------------------------------------
// Elementwise prep kernels (grid-stride)
// ---------------------------------------------------------------------------
__global__ void k_zero_bf16(ushort* p, long n) {
  for (long i = blockIdx.x * 256 + threadIdx.x; i < n; i += (long)gridDim.x * 256) p[i] = 0;
}
// xpad[b][p][d] = p in [4,516) ? bf16(x[b][p-4][d]) : 0
__global__ void k_fill_xpad(const float* __restrict__ x, ushort* __restrict__ xp) {
  const long n = (long)BB * LPAD * DD;
  for (long i = blockIdx.x * 256 + threadIdx.x; i < n; i += (long)gridDim.x * 256) {
    int d = (int)(i & 511);
    long rest = i >> 9;
    int p = (int)(rest % LPAD);
    int b = (int)(rest / LPAD);
    float v = 0.f;
    if (p >= 4 && p < 516) v = x[((long)b * LL + (p - 4)) * DD + d];
    xp[i] = f2bf(v);
  }
}
// wpack[k][o][i] = w[o][i][k]  (conv weight -> per-segment B^T layout [N=o][K=i])
__global__ void k_pack_convw(const float* __restrict__ w, ushort* __restrict__ wp) {
  const long n = (long)DD * DD * 9;
  for (long idx = blockIdx.x * 256 + threadIdx.x; idx < n; idx += (long)gridDim.x * 256) {
    int i = (int)(idx & 511);
    int o = (int)((idx >> 9) & 511);
    int k = (int)(idx >> 18);
    wp[idx] = f2bf(w[((long)o * DD + i) * 9 + k]);
  }
}
// wihx[n][i] = w_ih[n][i], n<3072, i<512 (x-part of w_ih, B^T layout)
__global__ void k_pack_wihx(const float* __restrict__ w_ih, ushort* __restrict__ wp) {
  const long n = (long)3 * DD2 * DD;
  for (long idx = blockIdx.x * 256 + threadIdx.x; idx < n; idx += (long)gridDim.x * 256) {
    int i = (int)(idx & 511);
    int nr = (int)(idx >> 9);
    wp[idx] = f2bf(w_ih[(long)nr * 1536 + i]);
  }
}
__global__ void k_pack_bf16(const float* __restrict__ s, ushort* __restrict__ d, long n) {
  for (long i = blockIdx.x * 256 + threadIdx.x; i < n; i += (long)gridDim.x * 256) d[i] = f2bf(s[i]);
}
// GRU weights in exact B-fragment order (layout unchanged; ks=32 unused in scan).
__global__ void k_pack_gru(const float* __restrict__ w_ih, const float* __restrict__ w_hh,
                           const float* __restrict__ b_hh, ushort* __restrict__ wp) {
  const long n = (long)64 * 6 * GRU_KSTEPS * 64 * 8;
  for (long idx = blockIdx.x * 256 + threadIdx.x; idx < n; idx += (long)gridDim.x * 256) {
    int j = (int)(idx & 7);
    int lane = (int)((idx >> 3) & 63);
    long r9 = idx >> 9;
    int ks = (int)(r9 % GRU_KSTEPS);
    long tmp = r9 / GRU_KSTEPS;
    int s = (int)(tmp % 6);
    int blk = (int)(tmp / 6);
    int k = ks * 32 + ((lane >> 4) << 3) + j;
    int u = blk * 16 + (lane & 15);
    float v = 0.f;
    if (s < 3) {
      if (k < 1024) v = w_ih[((long)(s * DD2 + u)) * 1536 + 512 + k];
    } else {
      int nr = (s - 3) * DD2 + u;
      if (k < 1024) v = w_hh[(long)nr * DD2 + k];
      else if (k == 1024) v = b_hh[nr];
    }
    wp[idx] = f2bf(v);
  }
}
// Zero hbuf[0] (h0 = 0, frag order) and the 64 padded flag lines.
__global__ void k_init_hbuf(ushort* hb, unsigned* flags) {
  int i = blockIdx.x * 256 + threadIdx.x;
  if (i < 16384) hb[i] = 0;
  if (i < 1024) flags[i] = 0u;
}

// ---------------------------------------------------------------------------
// Generic 128x128 bf16 MFMA GEMM.
// MODE: 0 +bias->f32 ; 1 +bias->bf16 ; 2 +bias->f32 ; 3 exp(+bias)->f32 ;
//       4 +bias->bf16 in packed gix layout [t][ublock][slice][b][u_local]
// ---------------------------------------------------------------------------
template <int MODE, int AMAP>
__global__ __launch_bounds__(256) void gemm128(
    const ushort* __restrict__ A, int lda, long segAoff,
    const ushort* __restrict__ Bt, int ldb, long segBoff,
    int nseg, int kseg, void* __restrict__ Cout, int ldc,
    const float* __restrict__ bias) {
  __shared__ ushort As[128 * 64];
  __shared__ ushort Bs[128 * 64];
  const int tid = threadIdx.x, lane = tid & 63, w = tid >> 6;
  const int wr = w >> 1, wc = w & 1;
  const int m0 = blockIdx.y * 128, n0 = blockIdx.x * 128;

  const ushort* Abase;
  if (AMAP == 1) {
    int b = m0 >> 9, l = m0 & 511;
    Abase = A + ((long)(b * LPAD + l)) * DD;
  } else {
    Abase = A + (long)m0 * lda;
  }
  const ushort* Bbase = Bt + (long)n0 * ldb;

  f32x4 acc[4][4];
#pragma unroll
  for (int i = 0; i < 4; i++)
#pragma unroll
    for (int j = 0; j < 4; j++) acc[i][j] = {0.f, 0.f, 0.f, 0.f};

  for (int seg = 0; seg < nseg; ++seg) {
    const ushort* Aseg = Abase + (long)seg * segAoff;
    const ushort* Bseg = Bbase + (long)seg * segBoff;
    for (int k0 = 0; k0 < kseg; k0 += 64) {
#pragma unroll
      for (int it = 0; it < 4; ++it) {
        int chunk = it * 256 + tid;
        int r = chunk >> 3, cc = chunk & 7;
        int sc = cc ^ (r & 7);
        *(short8*)&As[(size_t)chunk * 8] = *(const short8*)(Aseg + (long)r * lda + k0 + sc * 8);
        *(short8*)&Bs[(size_t)chunk * 8] = *(const short8*)(Bseg + (long)r * ldb + k0 + sc * 8);
      }
      __syncthreads();
#pragma unroll
      for (int kk = 0; kk < 2; ++kk) {
        short8 af[4], bfv[4];
#pragma unroll
        for (int m = 0; m < 4; m++) {
          int row = wr * 64 + m * 16 + (lane & 15);
          int ch = (kk * 4 + (lane >> 4)) ^ (row & 7);
          af[m] = *(const short8*)&As[(size_t)(row * 8 + ch) * 8];
        }
#pragma unroll
        for (int nn = 0; nn < 4; nn++) {
          int row = wc * 64 + nn * 16 + (lane & 15);
          int ch = (kk * 4 + (lane >> 4)) ^ (row & 7);
          bfv[nn] = *(const short8*)&Bs[(size_t)(row * 8 + ch) * 8];
        }
#pragma unroll
        for (int m = 0; m < 4; m++)
#pragma unroll
          for (int nn = 0; nn < 4; nn++)
            acc[m][nn] = __builtin_amdgcn_mfma_f32_16x16x32_bf16(af[m], bfv[nn], acc[m][nn], 0, 0, 0);
      }
      __syncthreads();
    }
  }
  float bvals[4];
#pragma unroll
  for (int nn = 0; nn < 4; nn++) {
    int c = n0 + wc * 64 + nn * 16 + (lane & 15);
    bvals[nn] = bias[c];
  }
#pragma unroll
  for (int m = 0; m < 4; m++) {
    int rbase = m0 + wr * 64 + m * 16 + ((lane >> 4) << 2);
#pragma unroll
    for (int nn = 0; nn < 4; nn++) {
      int c = n0 + wc * 64 + nn * 16 + (lane & 15);
#pragma unroll
      for (int j = 0; j < 4; j++) {
        float v = acc[m][nn][j] + bvals[nn];
        long off = (long)(rbase + j) * ldc + c;
        if (MODE == 0) ((float*)Cout)[off] = v;
        else if (MODE == 1) ((ushort*)Cout)[off] = f2bf(v);
        else if (MODE == 2) ((float*)Cout)[off] = v;
        else if (MODE == 3) ((float*)Cout)[off] = expf(v);
        else {
          // MODE 4: packed gix for gru_scan. row=(b*512+t), col=(s*1024+u)
          int r = rbase + j;
          int bb = r >> 9, tt = r & 511, ss = c >> 10, uu = c & 1023;
          long o2 = ((((long)(tt * 64 + (uu >> 4))) * 3 + ss) << 8) + (bb << 4) + (uu & 15);
          ((ushort*)Cout)[o2] = f2bf(v);
        }
      }
    }
  }
}

// ---------------------------------------------------------------------------
// LayerNorm(D=512) + ReLU (unchanged).
// ---------------------------------------------------------------------------
template <int DSTPAD>
__global__ __launch_bounds__(256) void ln_relu(
    const float* __restrict__ y, const float* __restrict__ g,
    const float* __restrict__ be, ushort* __restrict__ dst) {
  const int r = blockIdx.x, tid = threadIdx.x;
  float v0 = y[(long)r * DD + tid];
  float v1 = y[(long)r * DD + 256 + tid];
  float s = v0 + v1, sq = v0 * v0 + v1 * v1;
#pragma unroll
  for (int o = 32; o; o >>= 1) { s += __shfl_down(s, o); sq += __shfl_down(sq, o); }
  __shared__ float red[8];
  int w = tid >> 6, lane = tid & 63;
  if (lane == 0) { red[w] = s; red[4 + w] = sq; }
  __syncthreads();
  if (tid == 0) {
    float ts = 0.f, tq = 0.f;
#pragma unroll
    for (int i = 0; i < 4; i++) { ts += red[i]; tq += red[4 + i]; }
    red[0] = ts; red[1] = tq;
  }
  __syncthreads();
  float mean = red[0] * (1.f / 512.f);
  float var = red[1] * (1.f / 512.f) - mean * mean;
  float rs = rsqrtf(var + 1e-5f);
  long dbase;
  if (DSTPAD) { int b = r >> 9, l = r & 511; dbase = ((long)(b * LPAD + l + 4)) * DD; }
  else dbase = (long)r * DD;
  float o0 = fmaxf(0.f, (v0 - mean) * rs * g[tid] + be[tid]);
  float o1 = fmaxf(0.f, (v1 - mean) * rs * g[tid + 256] + be[tid + 256]);
  dst[dbase + tid] = f2bf(o0);
  dst[dbase + 256 + tid] = f2bf(o1);
}

// ---------------------------------------------------------------------------
// Persistent GRU scan, v8 = v3's EXACT sync skeleton (per-line flags, wave0
// poll + syncthreads broadcast, syncthreads-drained publish) + two validated
// data-path fixes:
//   1. ALL 6 weight slices preloaded and PINNED in registers via an
//      asm "+v" fence (v7 lesson: __restrict const lets the compiler sink
//      the loads into the loop -> 192KB/step L2 stream; the fence makes the
//      asm outputs the authoritative values, so rematerialization is illegal).
//   2. Packed gix [t][ublock][slice][b][u_local] (v7-validated: FETCH 181->97MB).
// h_seq store moved after the flag (pure output, off the drain path).
// ---------------------------------------------------------------------------
__global__ __launch_bounds__(256, 1) void gru_scan(
    const ushort* __restrict__ Wp, const ushort* __restrict__ gix2,
    const float* __restrict__ b_hh,
    ushort* __restrict__ hbuf, ushort* __restrict__ h_seq,
    unsigned* __restrict__ flags) {
  __shared__ float red[4 * 6 * 256];  // 24 KB
  const int tid = threadIdx.x, lane = tid & 63, w = tid >> 6, blk = blockIdx.x;
  const int j_c = w;                              // gate-phase j index = wave id
  const int u_local = lane & 15;
  const int b = ((lane >> 4) << 2) + j_c;         // gate-phase batch
  const int u = (blk << 4) + u_local;             // gate-phase unit
  // frag position of (u,b) in next step's A buffer: k=u
  const int lanep = ((blk & 1) * 2 + (u_local >> 3)) * 16 + b;
  const long hout_off = ((long)(blk >> 1) * 64 + lanep) * 8 + (u_local & 7);
  const ushort* wpw = Wp + (long)blk * 6 * GRU_KSTEPS * 512 + (long)lane * 8;
  const float bhr = b_hh[u], bhz = b_hh[DD2 + u], bhn = b_hh[2 * DD2 + u];
  float hold = 0.f;

  // Preload ALL 6 weight slices into registers (~192 VGPRs), then pin them:
  // the asm "+v" redefines each value, so later uses must come from these
  // registers — the compiler cannot sink/remat the loads into the t-loop.
  short8 wr0[8], wr1[8], wr2[8], wr3[8], wr4[8], wr5[8];
#pragma unroll
  for (int i = 0; i < 8; ++i) {
    const int ks = i * 4 + w;
    wr0[i] = *(const short8*)(wpw + (long)(0 * GRU_KSTEPS + ks) * 512);
    wr1[i] = *(const short8*)(wpw + (long)(1 * GRU_KSTEPS + ks) * 512);
    wr2[i] = *(const short8*)(wpw + (long)(2 * GRU_KSTEPS + ks) * 512);
    wr3[i] = *(const short8*)(wpw + (long)(3 * GRU_KSTEPS + ks) * 512);
    wr4[i] = *(const short8*)(wpw + (long)(4 * GRU_KSTEPS + ks) * 512);
    wr5[i] = *(const short8*)(wpw + (long)(5 * GRU_KSTEPS + ks) * 512);
  }
#pragma unroll
  for (int i = 0; i < 8; ++i) {
    asm volatile("" : "+v"(wr0[i]), "+v"(wr1[i]), "+v"(wr2[i]),
                      "+v"(wr3[i]), "+v"(wr4[i]), "+v"(wr5[i]));
  }

  const int gofs = (b << 4) + u_local;
  for (int t = 0; t < LL; ++t) {
    // gate-input loads: one contiguous 1536B chunk per (blk,t); issued BEFORE
    // the poll so HBM latency overlaps the wait. Nontemporal (pure stream).
    const long gbase = ((long)(t * 64 + blk) * 3) << 8;
    const float gx_r = bf2f(__builtin_nontemporal_load(gix2 + gbase + gofs));
    const float gx_z = bf2f(__builtin_nontemporal_load(gix2 + gbase + 256 + gofs));
    const float gx_n = bf2f(__builtin_nontemporal_load(gix2 + gbase + 512 + gofs));

    // Detect (v3): wave0 polls the 64 per-line flags; syncthreads broadcast.
    if (t > 0) {
      if (w == 0) {
        const unsigned tgt = (unsigned)t;
        while (1) {
          unsigned f = __hip_atomic_load(&flags[lane << 4], __ATOMIC_RELAXED,
                                         __HIP_MEMORY_SCOPE_AGENT);
          if (__all((int)(f >= tgt))) break;
          __builtin_amdgcn_s_sleep(1);
        }
      }
      __syncthreads();
    }

    const ushort* hb = hbuf + ((long)t << 14);
    f32x4 acc0 = {0.f,0.f,0.f,0.f}, acc1 = acc0, acc2 = acc0,
          acc3 = acc0, acc4 = acc0, acc5 = acc0;
#pragma unroll
    for (int i = 0; i < 8; ++i) {
      const int ks = i * 4 + w;
      unsigned long long* ap = (unsigned long long*)(hb + (((long)ks * 64 + lane) << 3));
      union { unsigned long long q[2]; short8 v; } cv;
      cv.q[0] = __hip_atomic_load(ap,     __ATOMIC_RELAXED, __HIP_MEMORY_SCOPE_AGENT);
      cv.q[1] = __hip_atomic_load(ap + 1, __ATOMIC_RELAXED, __HIP_MEMORY_SCOPE_AGENT);
      acc0 = __builtin_amdgcn_mfma_f32_16x16x32_bf16(cv.v, wr0[i], acc0, 0, 0, 0);
      acc1 = __builtin_amdgcn_mfma_f32_16x16x32_bf16(cv.v, wr1[i], acc1, 0, 0, 0);
      acc2 = __builtin_amdgcn_mfma_f32_16x16x32_bf16(cv.v, wr2[i], acc2, 0, 0, 0);
      acc3 = __builtin_amdgcn_mfma_f32_16x16x32_bf16(cv.v, wr3[i], acc3, 0, 0, 0);
      acc4 = __builtin_amdgcn_mfma_f32_16x16x32_bf16(cv.v, wr4[i], acc4, 0, 0, 0);
      acc5 = __builtin_amdgcn_mfma_f32_16x16x32_bf16(cv.v, wr5[i], acc5, 0, 0, 0);
    }
    // Cross-wave reduce, transposed layout (conflict-free both sides).
#pragma unroll
    for (int j = 0; j < 4; ++j) {
      red[((w * 6 + 0) << 8) + (j << 6) + lane] = acc0[j];
      red[((w * 6 + 1) << 8) + (j << 6) + lane] = acc1[j];
      red[((w * 6 + 2) << 8) + (j << 6) + lane] = acc2[j];
      red[((w * 6 + 3) << 8) + (j << 6) + lane] = acc3[j];
      red[((w * 6 + 4) << 8) + (j << 6) + lane] = acc4[j];
      red[((w * 6 + 5) << 8) + (j << 6) + lane] = acc5[j];
    }
    __syncthreads();
    float v0 = 0.f, v1 = 0.f, v2 = 0.f, v3 = 0.f, v4 = 0.f, v5 = 0.f;
#pragma unroll
    for (int wv = 0; wv < 4; ++wv) {
      const int base = ((wv * 6) << 8) + (j_c << 6) + lane;
      v0 += red[base];
      v1 += red[base + 256];
      v2 += red[base + 512];
      v3 += red[base + 768];
      v4 += red[base + 1024];
      v5 += red[base + 1280];
    }
    // gates (b_hh folded in as scalars; n-gate bias inside r*(.) per torch GRUCell)
    const float rg = 1.f / (1.f + __expf(-(gx_r + v0 + v3 + bhr)));
    const float zg = 1.f / (1.f + __expf(-(gx_z + v1 + v4 + bhz)));
    const float nx = gx_n + v2 + rg * (v5 + bhn);
    const float ng = 1.f - 2.f / (__expf(2.f * nx) + 1.f);
    const float hn = (1.f - zg) * ng + zg * hold;
    hold = hn;
    const ushort h16 = f2bf(hn);
    if (t < LL - 1) {
      // publish h (write-through to the coherence point, relaxed)
      __hip_atomic_store(hbuf + (((long)(t + 1)) << 14) + hout_off, h16,
                         __ATOMIC_RELAXED, __HIP_MEMORY_SCOPE_AGENT);
      __syncthreads();  // drains vmcnt(0) for every wave before the flag
      if (tid == 0)
        __hip_atomic_store(&flags[blk << 4], (unsigned)(t + 1), __ATOMIC_RELAXED,
                           __HIP_MEMORY_SCOPE_AGENT);
    }
    // pure output, off the critical path (issued after the flag)
    __builtin_nontemporal_store(h16, h_seq + ((long)b * LL + t) * DD2 + u);
  }
}

// ---------------------------------------------------------------------------
// Mixture-weight head (unchanged).
// ---------------------------------------------------------------------------
__global__ __launch_bounds__(256) void w_head(
    const ushort* __restrict__ h_seq, const float* __restrict__ ww,
    const float* __restrict__ wb, float* __restrict__ out) {
  const int tid = threadIdx.x, lane = tid & 63, w = tid >> 6;
  const long r = (long)blockIdx.x * 4 + w;
  float s[KMIX];
#pragma unroll
  for (int k = 0; k < KMIX; k++) s[k] = 0.f;
  for (int u = lane; u < DD2; u += 64) {
    float hv = bf2f(h_seq[r * DD2 + u]);
#pragma unroll
    for (int k = 0; k < KMIX; k++) s[k] += hv * ww[(long)k * DD2 + u];
  }
#pragma unroll
  for (int k = 0; k < KMIX; k++)
#pragma unroll
    for (int o = 32; o; o >>= 1) s[k] += __shfl_xor(s[k], o);
#pragma unroll
  for (int k = 0; k < KMIX; k++) s[k] += wb[k];
  float m = s[0];
#pragma unroll
  for (int k = 1; k < KMIX; k++) m = fmaxf(m, s[k]);
  float esum = 0.f;
#pragma unroll
  for (int k = 0; k < KMIX; k++) { s[k] = expf(s[k] - m); esum += s[k]; }
  float mine = 0.f;
#pragma unroll
  for (int k = 0; k < KMIX; k++) if (lane == k) mine = s[k];
  if (lane < KMIX) out[r * KMIX + lane] = mine / esum;
}

// ---------------------------------------------------------------------------
extern "C" void kernel_launch(void* const* d_in, const int* in_sizes, int n_in,
                              void* d_out, int out_size, void* d_ws, size_t ws_size,
                              hipStream_t stream) {
  const float* h_text     = (const float*)d_in[0];
  const float* conv1_w    = (const float*)d_in[1];
  const float* conv1_b    = (const float*)d_in[2];
  const float* ln1_g      = (const float*)d_in[3];
  const float* ln1_b      = (const float*)d_in[4];
  const float* conv2_w    = (const float*)d_in[5];
  const float* conv2_b    = (const float*)d_in[6];
  const float* ln2_g      = (const float*)d_in[7];
  const float* ln2_b      = (const float*)d_in[8];
  const float* w_ih       = (const float*)d_in[9];
  const float* w_hh       = (const float*)d_in[10];
  const float* b_ih       = (const float*)d_in[11];
  const float* b_hh       = (const float*)d_in[12];
  const float* mdn_w_w    = (const float*)d_in[13];
  const float* mdn_w_b    = (const float*)d_in[14];
  const float* mdn_sig_w  = (const float*)d_in[15];
  const float* mdn_sig_b  = (const float*)d_in[16];
  const float* mdn_mu_w   = (const float*)d_in[17];
  const float* mdn_mu_b   = (const float*)d_in[18];
  float* out = (float*)d_out;

  char* ws = (char*)d_ws;
  size_t off = 0;
  auto take = [&](size_t bytes) {
    void* p = ws + off;
    off += (bytes + 255) & ~(size_t)255;
    return p;
  };
  ushort* xpad1  = (ushort*)take((size_t)BB * LPAD * DD * 2);
  ushort* xpad2  = (ushort*)take((size_t)BB * LPAD * DD * 2);
  ushort* wpack1 = (ushort*)take((size_t)DD * DD * 9 * 2);
  ushort* wpack2 = (ushort*)take((size_t)DD * DD * 9 * 2);
  float*  ybuf   = (float*) take((size_t)BB * LL * DD * 4);
  ushort* x2     = (ushort*)take((size_t)BB * LL * DD * 2);
  ushort* wihx   = (ushort*)take((size_t)3 * DD2 * DD * 2);
  ushort* gix    = (ushort*)take((size_t)BB * LL * 3 * DD2 * 2);   // packed layout
  ushort* Wp     = (ushort*)take((size_t)64 * 6 * GRU_KSTEPS * 64 * 8 * 2);
  ushort* hseq   = (ushort*)take((size_t)BB * LL * DD2 * 2);
  ushort* mdnmu  = (ushort*)take((size_t)KMIX * DD2 * DD2 * 2);
  ushort* mdnsg  = (ushort*)take((size_t)KMIX * DD2 * DD2 * 2);
  ushort* hbuf   = (ushort*)take((size_t)512 * 16384 * 2);   // 512 write-once frag buffers
  unsigned* flags = (unsigned*)take(64 * 16 * 4);            // 64 flags, 64B-padded lines

  const long sigma_off = (long)BB * LL * KMIX;                    // 65536
  const long mu_off    = sigma_off + (long)BB * LL * KMIX * DD2;  // 67174400

  // --- prep / packing ---
  k_fill_xpad<<<2048, 256, 0, stream>>>(h_text, xpad1);
  k_zero_bf16<<<2048, 256, 0, stream>>>(xpad2, (long)BB * LPAD * DD);
  k_pack_convw<<<2048, 256, 0, stream>>>(conv1_w, wpack1);
  k_pack_convw<<<2048, 256, 0, stream>>>(conv2_w, wpack2);
  k_pack_wihx<<<2048, 256, 0, stream>>>(w_ih, wihx);
  k_pack_gru<<<2048, 256, 0, stream>>>(w_ih, w_hh, b_hh, Wp);
  k_pack_bf16<<<2048, 256, 0, stream>>>(mdn_mu_w, mdnmu, (long)KMIX * DD2 * DD2);
  k_pack_bf16<<<2048, 256, 0, stream>>>(mdn_sig_w, mdnsg, (long)KMIX * DD2 * DD2);
  k_init_hbuf<<<64, 256, 0, stream>>>(hbuf, flags);

  // --- conv block 1: y = conv(xpad1) + b ; LN+ReLU -> xpad2 ---
  gemm128<0, 1><<<dim3(4, 64), 256, 0, stream>>>(xpad1, DD, DD, wpack1, DD, (long)DD * DD, 9, DD,
                                                 ybuf, DD, conv1_b);
  ln_relu<1><<<BB * LL, 256, 0, stream>>>(ybuf, ln1_g, ln1_b, xpad2);

  // --- conv block 2 -> x2 (GRU input, plain bf16 [8192,512]) ---
  gemm128<0, 1><<<dim3(4, 64), 256, 0, stream>>>(xpad2, DD, DD, wpack2, DD, (long)DD * DD, 9, DD,
                                                 ybuf, DD, conv2_b);
  ln_relu<0><<<BB * LL, 256, 0, stream>>>(ybuf, ln2_g, ln2_b, x2);

  // --- gi_x = x2 @ w_ih[:, :512]^T + b_ih -> PACKED gix layout (MODE=4) ---
  gemm128<4, 0><<<dim3(24, 64), 256, 0, stream>>>(x2, DD, 0, wihx, DD, 0, 1, DD,
                                                  gix, 3 * DD2, b_ih);

  // --- persistent GRU scan (v3 sync skeleton + pinned weights + packed gix) ---
  gru_scan<<<64, 256, 0, stream>>>(Wp, gix, b_hh, hbuf, hseq, flags);

  // --- MDN heads ---
  gemm128<3, 0><<<dim3(64, 64), 256, 0, stream>>>(hseq, DD2, 0, mdnsg, DD2, 0, 1, DD2,
                                                  out + sigma_off, KMIX * DD2, mdn_sig_b);
  gemm128<2, 0><<<dim3(64, 64), 256, 0, stream>>>(hseq, DD2, 0, mdnmu, DD2, 0, 1, DD2,
                                                  out + mu_off, KMIX * DD2, mdn_mu_b);
  w_head<<<BB * LL / 4, 256, 0, stream>>>(hseq, mdn_w_w, mdn_w_b, out);
}

// Round 9
// 1931.946 us; speedup vs baseline: 1.6148x; 1.3836x over previous
//
#include <hip/hip_runtime.h>
#include <hip/hip_bf16.h>
#include <math.h>

// Problem constants
#define BB 16
#define LL 512
#define DD 512
#define DD2 1024
#define KMIX 8
#define LPAD 520          // L + 8 pad rows (4 each side) for KS=9 conv
#define GRU_KSTEPS 33     // Wp layout keeps 33 k-steps; scan uses 0..31 (bias via scalars)

typedef __attribute__((ext_vector_type(8))) short short8;
typedef __attribute__((ext_vector_type(4))) float f32x4;
typedef unsigned short ushort;

__device__ __forceinline__ float bf2f(ushort u) {
  union { float f; unsigned i; } v; v.i = ((unsigned)u) << 16; return v.f;
}
__device__ __forceinline__ ushort f2bf(float f) {
  union { float f; unsigned i; } v; v.f = f;
  unsigned i = v.i;
  unsigned r = i + 0x7FFF + ((i >> 16) & 1);   // RNE
  return (ushort)(r >> 16);
}

// ---------------------------------------------------------------------------
// Elementwise prep kernels (grid-stride)
// ---------------------------------------------------------------------------
__global__ void k_zero_bf16(ushort* p, long n) {
  for (long i = blockIdx.x * 256 + threadIdx.x; i < n; i += (long)gridDim.x * 256) p[i] = 0;
}
// xpad[b][p][d] = p in [4,516) ? bf16(x[b][p-4][d]) : 0
__global__ void k_fill_xpad(const float* __restrict__ x, ushort* __restrict__ xp) {
  const long n = (long)BB * LPAD * DD;
  for (long i = blockIdx.x * 256 + threadIdx.x; i < n; i += (long)gridDim.x * 256) {
    int d = (int)(i & 511);
    long rest = i >> 9;
    int p = (int)(rest % LPAD);
    int b = (int)(rest / LPAD);
    float v = 0.f;
    if (p >= 4 && p < 516) v = x[((long)b * LL + (p - 4)) * DD + d];
    xp[i] = f2bf(v);
  }
}
// wpack[k][o][i] = w[o][i][k]  (conv weight -> per-segment B^T layout [N=o][K=i])
__global__ void k_pack_convw(const float* __restrict__ w, ushort* __restrict__ wp) {
  const long n = (long)DD * DD * 9;
  for (long idx = blockIdx.x * 256 + threadIdx.x; idx < n; idx += (long)gridDim.x * 256) {
    int i = (int)(idx & 511);
    int o = (int)((idx >> 9) & 511);
    int k = (int)(idx >> 18);
    wp[idx] = f2bf(w[((long)o * DD + i) * 9 + k]);
  }
}
// wihx[n][i] = w_ih[n][i], n<3072, i<512 (x-part of w_ih, B^T layout)
__global__ void k_pack_wihx(const float* __restrict__ w_ih, ushort* __restrict__ wp) {
  const long n = (long)3 * DD2 * DD;
  for (long idx = blockIdx.x * 256 + threadIdx.x; idx < n; idx += (long)gridDim.x * 256) {
    int i = (int)(idx & 511);
    int nr = (int)(idx >> 9);
    wp[idx] = f2bf(w_ih[(long)nr * 1536 + i]);
  }
}
__global__ void k_pack_bf16(const float* __restrict__ s, ushort* __restrict__ d, long n) {
  for (long i = blockIdx.x * 256 + threadIdx.x; i < n; i += (long)gridDim.x * 256) d[i] = f2bf(s[i]);
}
// GRU weights in exact B-fragment order (layout unchanged; ks=32 unused in scan).
__global__ void k_pack_gru(const float* __restrict__ w_ih, const float* __restrict__ w_hh,
                           const float* __restrict__ b_hh, ushort* __restrict__ wp) {
  const long n = (long)64 * 6 * GRU_KSTEPS * 64 * 8;
  for (long idx = blockIdx.x * 256 + threadIdx.x; idx < n; idx += (long)gridDim.x * 256) {
    int j = (int)(idx & 7);
    int lane = (int)((idx >> 3) & 63);
    long r9 = idx >> 9;
    int ks = (int)(r9 % GRU_KSTEPS);
    long tmp = r9 / GRU_KSTEPS;
    int s = (int)(tmp % 6);
    int blk = (int)(tmp / 6);
    int k = ks * 32 + ((lane >> 4) << 3) + j;
    int u = blk * 16 + (lane & 15);
    float v = 0.f;
    if (s < 3) {
      if (k < 1024) v = w_ih[((long)(s * DD2 + u)) * 1536 + 512 + k];
    } else {
      int nr = (s - 3) * DD2 + u;
      if (k < 1024) v = w_hh[(long)nr * DD2 + k];
      else if (k == 1024) v = b_hh[nr];
    }
    wp[idx] = f2bf(v);
  }
}
// Zero hbuf[0] (h0 = 0, frag order) and the 64 padded flag lines.
__global__ void k_init_hbuf(ushort* hb, unsigned* flags) {
  int i = blockIdx.x * 256 + threadIdx.x;
  if (i < 16384) hb[i] = 0;
  if (i < 1024) flags[i] = 0u;
}

// ---------------------------------------------------------------------------
// Generic 128x128 bf16 MFMA GEMM.
// MODE: 0 +bias->f32 ; 1 +bias->bf16 ; 2 +bias->f32 ; 3 exp(+bias)->f32 ;
//       4 +bias->bf16 in packed gix layout [t][ublock][slice][b][u_local]
// ---------------------------------------------------------------------------
template <int MODE, int AMAP>
__global__ __launch_bounds__(256) void gemm128(
    const ushort* __restrict__ A, int lda, long segAoff,
    const ushort* __restrict__ Bt, int ldb, long segBoff,
    int nseg, int kseg, void* __restrict__ Cout, int ldc,
    const float* __restrict__ bias) {
  __shared__ ushort As[128 * 64];
  __shared__ ushort Bs[128 * 64];
  const int tid = threadIdx.x, lane = tid & 63, w = tid >> 6;
  const int wr = w >> 1, wc = w & 1;
  const int m0 = blockIdx.y * 128, n0 = blockIdx.x * 128;

  const ushort* Abase;
  if (AMAP == 1) {
    int b = m0 >> 9, l = m0 & 511;
    Abase = A + ((long)(b * LPAD + l)) * DD;
  } else {
    Abase = A + (long)m0 * lda;
  }
  const ushort* Bbase = Bt + (long)n0 * ldb;

  f32x4 acc[4][4];
#pragma unroll
  for (int i = 0; i < 4; i++)
#pragma unroll
    for (int j = 0; j < 4; j++) acc[i][j] = {0.f, 0.f, 0.f, 0.f};

  for (int seg = 0; seg < nseg; ++seg) {
    const ushort* Aseg = Abase + (long)seg * segAoff;
    const ushort* Bseg = Bbase + (long)seg * segBoff;
    for (int k0 = 0; k0 < kseg; k0 += 64) {
#pragma unroll
      for (int it = 0; it < 4; ++it) {
        int chunk = it * 256 + tid;
        int r = chunk >> 3, cc = chunk & 7;
        int sc = cc ^ (r & 7);
        *(short8*)&As[(size_t)chunk * 8] = *(const short8*)(Aseg + (long)r * lda + k0 + sc * 8);
        *(short8*)&Bs[(size_t)chunk * 8] = *(const short8*)(Bseg + (long)r * ldb + k0 + sc * 8);
      }
      __syncthreads();
#pragma unroll
      for (int kk = 0; kk < 2; ++kk) {
        short8 af[4], bfv[4];
#pragma unroll
        for (int m = 0; m < 4; m++) {
          int row = wr * 64 + m * 16 + (lane & 15);
          int ch = (kk * 4 + (lane >> 4)) ^ (row & 7);
          af[m] = *(const short8*)&As[(size_t)(row * 8 + ch) * 8];
        }
#pragma unroll
        for (int nn = 0; nn < 4; nn++) {
          int row = wc * 64 + nn * 16 + (lane & 15);
          int ch = (kk * 4 + (lane >> 4)) ^ (row & 7);
          bfv[nn] = *(const short8*)&Bs[(size_t)(row * 8 + ch) * 8];
        }
#pragma unroll
        for (int m = 0; m < 4; m++)
#pragma unroll
          for (int nn = 0; nn < 4; nn++)
            acc[m][nn] = __builtin_amdgcn_mfma_f32_16x16x32_bf16(af[m], bfv[nn], acc[m][nn], 0, 0, 0);
      }
      __syncthreads();
    }
  }
  float bvals[4];
#pragma unroll
  for (int nn = 0; nn < 4; nn++) {
    int c = n0 + wc * 64 + nn * 16 + (lane & 15);
    bvals[nn] = bias[c];
  }
#pragma unroll
  for (int m = 0; m < 4; m++) {
    int rbase = m0 + wr * 64 + m * 16 + ((lane >> 4) << 2);
#pragma unroll
    for (int nn = 0; nn < 4; nn++) {
      int c = n0 + wc * 64 + nn * 16 + (lane & 15);
#pragma unroll
      for (int j = 0; j < 4; j++) {
        float v = acc[m][nn][j] + bvals[nn];
        long off = (long)(rbase + j) * ldc + c;
        if (MODE == 0) ((float*)Cout)[off] = v;
        else if (MODE == 1) ((ushort*)Cout)[off] = f2bf(v);
        else if (MODE == 2) ((float*)Cout)[off] = v;
        else if (MODE == 3) ((float*)Cout)[off] = expf(v);
        else {
          // MODE 4: packed gix for gru_scan. row=(b*512+t), col=(s*1024+u)
          int r = rbase + j;
          int bb = r >> 9, tt = r & 511, ss = c >> 10, uu = c & 1023;
          long o2 = ((((long)(tt * 64 + (uu >> 4))) * 3 + ss) << 8) + (bb << 4) + (uu & 15);
          ((ushort*)Cout)[o2] = f2bf(v);
        }
      }
    }
  }
}

// ---------------------------------------------------------------------------
// LayerNorm(D=512) + ReLU (unchanged).
// ---------------------------------------------------------------------------
template <int DSTPAD>
__global__ __launch_bounds__(256) void ln_relu(
    const float* __restrict__ y, const float* __restrict__ g,
    const float* __restrict__ be, ushort* __restrict__ dst) {
  const int r = blockIdx.x, tid = threadIdx.x;
  float v0 = y[(long)r * DD + tid];
  float v1 = y[(long)r * DD + 256 + tid];
  float s = v0 + v1, sq = v0 * v0 + v1 * v1;
#pragma unroll
  for (int o = 32; o; o >>= 1) { s += __shfl_down(s, o); sq += __shfl_down(sq, o); }
  __shared__ float red[8];
  int w = tid >> 6, lane = tid & 63;
  if (lane == 0) { red[w] = s; red[4 + w] = sq; }
  __syncthreads();
  if (tid == 0) {
    float ts = 0.f, tq = 0.f;
#pragma unroll
    for (int i = 0; i < 4; i++) { ts += red[i]; tq += red[4 + i]; }
    red[0] = ts; red[1] = tq;
  }
  __syncthreads();
  float mean = red[0] * (1.f / 512.f);
  float var = red[1] * (1.f / 512.f) - mean * mean;
  float rs = rsqrtf(var + 1e-5f);
  long dbase;
  if (DSTPAD) { int b = r >> 9, l = r & 511; dbase = ((long)(b * LPAD + l + 4)) * DD; }
  else dbase = (long)r * DD;
  float o0 = fmaxf(0.f, (v0 - mean) * rs * g[tid] + be[tid]);
  float o1 = fmaxf(0.f, (v1 - mean) * rs * g[tid + 256] + be[tid + 256]);
  dst[dbase + tid] = f2bf(o0);
  dst[dbase + 256 + tid] = f2bf(o1);
}

// ---------------------------------------------------------------------------
// Persistent GRU scan, v9. 64 blocks x 512 threads (8 waves), co-resident.
// v3's EXACT sync skeleton. The weight-residency fix: with 8 waves each wave
// covers 4 k-steps, so ALL 6 slices fit in 96 payload VGPRs/wave — the size
// v3 proved the allocator keeps register-resident (v7: __restrict sink at
// 192; v8: spill-to-scratch at 192+pin). Zero weight memory traffic in-loop.
// Waves 0-3 additionally run the gate phase (v3 mapping); 4-7 MFMA only.
// Reduce buffer 8x6x256 f32 = 48 KB static LDS.
// ---------------------------------------------------------------------------
__global__ __launch_bounds__(512, 1) void gru_scan(
    const ushort* __restrict__ Wp, const ushort* __restrict__ gix2,
    const float* __restrict__ b_hh,
    ushort* __restrict__ hbuf, ushort* __restrict__ h_seq,
    unsigned* __restrict__ flags) {
  __shared__ float red[8 * 6 * 256];  // 48 KB
  const int tid = threadIdx.x, lane = tid & 63, w = tid >> 6, blk = blockIdx.x;
  const int j_c = w;                              // gate-phase j index (waves 0-3)
  const int u_local = lane & 15;
  const int b = ((lane >> 4) << 2) + (j_c & 3);   // gate-phase batch (valid for w<4)
  const int u = (blk << 4) + u_local;             // gate-phase unit
  // frag position of (u,b) in next step's A buffer: k=u
  const int lanep = ((blk & 1) * 2 + (u_local >> 3)) * 16 + b;
  const long hout_off = ((long)(blk >> 1) * 64 + lanep) * 8 + (u_local & 7);
  const ushort* wpw = Wp + (long)blk * 6 * GRU_KSTEPS * 512 + (long)lane * 8;
  const float bhr = b_hh[u], bhz = b_hh[DD2 + u], bhn = b_hh[2 * DD2 + u];
  float hold = 0.f;

  // Preload ALL 6 slices for this wave's 4 k-steps: 24 short8 = 96 VGPRs.
  short8 wr0[4], wr1[4], wr2[4], wr3[4], wr4[4], wr5[4];
#pragma unroll
  for (int i = 0; i < 4; ++i) {
    const int ks = i * 8 + w;
    wr0[i] = *(const short8*)(wpw + (long)(0 * GRU_KSTEPS + ks) * 512);
    wr1[i] = *(const short8*)(wpw + (long)(1 * GRU_KSTEPS + ks) * 512);
    wr2[i] = *(const short8*)(wpw + (long)(2 * GRU_KSTEPS + ks) * 512);
    wr3[i] = *(const short8*)(wpw + (long)(3 * GRU_KSTEPS + ks) * 512);
    wr4[i] = *(const short8*)(wpw + (long)(4 * GRU_KSTEPS + ks) * 512);
    wr5[i] = *(const short8*)(wpw + (long)(5 * GRU_KSTEPS + ks) * 512);
  }

  const int gofs = (b << 4) + u_local;
  for (int t = 0; t < LL; ++t) {
    // gate-input loads (waves 0-3 only): one contiguous 1536B chunk per
    // (blk,t); issued BEFORE the poll so HBM latency overlaps the wait.
    float gx_r = 0.f, gx_z = 0.f, gx_n = 0.f;
    if (w < 4) {
      const long gbase = ((long)(t * 64 + blk) * 3) << 8;
      gx_r = bf2f(__builtin_nontemporal_load(gix2 + gbase + gofs));
      gx_z = bf2f(__builtin_nontemporal_load(gix2 + gbase + 256 + gofs));
      gx_n = bf2f(__builtin_nontemporal_load(gix2 + gbase + 512 + gofs));
    }

    // Detect (v3): wave0 polls the 64 per-line flags; syncthreads broadcast.
    if (t > 0) {
      if (w == 0) {
        const unsigned tgt = (unsigned)t;
        while (1) {
          unsigned f = __hip_atomic_load(&flags[lane << 4], __ATOMIC_RELAXED,
                                         __HIP_MEMORY_SCOPE_AGENT);
          if (__all((int)(f >= tgt))) break;
          __builtin_amdgcn_s_sleep(1);
        }
      }
      __syncthreads();
    }

    const ushort* hb = hbuf + ((long)t << 14);
    f32x4 acc0 = {0.f,0.f,0.f,0.f}, acc1 = acc0, acc2 = acc0,
          acc3 = acc0, acc4 = acc0, acc5 = acc0;
#pragma unroll
    for (int i = 0; i < 4; ++i) {
      const int ks = i * 8 + w;
      unsigned long long* ap = (unsigned long long*)(hb + (((long)ks * 64 + lane) << 3));
      union { unsigned long long q[2]; short8 v; } cv;
      cv.q[0] = __hip_atomic_load(ap,     __ATOMIC_RELAXED, __HIP_MEMORY_SCOPE_AGENT);
      cv.q[1] = __hip_atomic_load(ap + 1, __ATOMIC_RELAXED, __HIP_MEMORY_SCOPE_AGENT);
      acc0 = __builtin_amdgcn_mfma_f32_16x16x32_bf16(cv.v, wr0[i], acc0, 0, 0, 0);
      acc1 = __builtin_amdgcn_mfma_f32_16x16x32_bf16(cv.v, wr1[i], acc1, 0, 0, 0);
      acc2 = __builtin_amdgcn_mfma_f32_16x16x32_bf16(cv.v, wr2[i], acc2, 0, 0, 0);
      acc3 = __builtin_amdgcn_mfma_f32_16x16x32_bf16(cv.v, wr3[i], acc3, 0, 0, 0);
      acc4 = __builtin_amdgcn_mfma_f32_16x16x32_bf16(cv.v, wr4[i], acc4, 0, 0, 0);
      acc5 = __builtin_amdgcn_mfma_f32_16x16x32_bf16(cv.v, wr5[i], acc5, 0, 0, 0);
    }
    // Cross-wave reduce, transposed layout (conflict-free both sides).
#pragma unroll
    for (int j = 0; j < 4; ++j) {
      red[((w * 6 + 0) << 8) + (j << 6) + lane] = acc0[j];
      red[((w * 6 + 1) << 8) + (j << 6) + lane] = acc1[j];
      red[((w * 6 + 2) << 8) + (j << 6) + lane] = acc2[j];
      red[((w * 6 + 3) << 8) + (j << 6) + lane] = acc3[j];
      red[((w * 6 + 4) << 8) + (j << 6) + lane] = acc4[j];
      red[((w * 6 + 5) << 8) + (j << 6) + lane] = acc5[j];
    }
    __syncthreads();
    ushort h16 = 0;
    if (w < 4) {
      float v0 = 0.f, v1 = 0.f, v2 = 0.f, v3 = 0.f, v4 = 0.f, v5 = 0.f;
#pragma unroll
      for (int wv = 0; wv < 8; ++wv) {
        const int base = ((wv * 6) << 8) + (j_c << 6) + lane;
        v0 += red[base];
        v1 += red[base + 256];
        v2 += red[base + 512];
        v3 += red[base + 768];
        v4 += red[base + 1024];
        v5 += red[base + 1280];
      }
      // gates (b_hh folded in as scalars; n-gate bias inside r*(.) per torch)
      const float rg = 1.f / (1.f + __expf(-(gx_r + v0 + v3 + bhr)));
      const float zg = 1.f / (1.f + __expf(-(gx_z + v1 + v4 + bhz)));
      const float nx = gx_n + v2 + rg * (v5 + bhn);
      const float ng = 1.f - 2.f / (__expf(2.f * nx) + 1.f);
      const float hn = (1.f - zg) * ng + zg * hold;
      hold = hn;
      h16 = f2bf(hn);
    }
    if (t < LL - 1) {
      if (w < 4)
        __hip_atomic_store(hbuf + (((long)(t + 1)) << 14) + hout_off, h16,
                           __ATOMIC_RELAXED, __HIP_MEMORY_SCOPE_AGENT);
      __syncthreads();  // drains vmcnt for every wave before the flag
      if (tid == 0)
        __hip_atomic_store(&flags[blk << 4], (unsigned)(t + 1), __ATOMIC_RELAXED,
                           __HIP_MEMORY_SCOPE_AGENT);
    }
    // pure output, off the critical path (issued after the flag)
    if (w < 4)
      __builtin_nontemporal_store(h16, h_seq + ((long)b * LL + t) * DD2 + u);
  }
}

// ---------------------------------------------------------------------------
// Mixture-weight head (unchanged).
// ---------------------------------------------------------------------------
__global__ __launch_bounds__(256) void w_head(
    const ushort* __restrict__ h_seq, const float* __restrict__ ww,
    const float* __restrict__ wb, float* __restrict__ out) {
  const int tid = threadIdx.x, lane = tid & 63, w = tid >> 6;
  const long r = (long)blockIdx.x * 4 + w;
  float s[KMIX];
#pragma unroll
  for (int k = 0; k < KMIX; k++) s[k] = 0.f;
  for (int u = lane; u < DD2; u += 64) {
    float hv = bf2f(h_seq[r * DD2 + u]);
#pragma unroll
    for (int k = 0; k < KMIX; k++) s[k] += hv * ww[(long)k * DD2 + u];
  }
#pragma unroll
  for (int k = 0; k < KMIX; k++)
#pragma unroll
    for (int o = 32; o; o >>= 1) s[k] += __shfl_xor(s[k], o);
#pragma unroll
  for (int k = 0; k < KMIX; k++) s[k] += wb[k];
  float m = s[0];
#pragma unroll
  for (int k = 1; k < KMIX; k++) m = fmaxf(m, s[k]);
  float esum = 0.f;
#pragma unroll
  for (int k = 0; k < KMIX; k++) { s[k] = expf(s[k] - m); esum += s[k]; }
  float mine = 0.f;
#pragma unroll
  for (int k = 0; k < KMIX; k++) if (lane == k) mine = s[k];
  if (lane < KMIX) out[r * KMIX + lane] = mine / esum;
}

// ---------------------------------------------------------------------------
extern "C" void kernel_launch(void* const* d_in, const int* in_sizes, int n_in,
                              void* d_out, int out_size, void* d_ws, size_t ws_size,
                              hipStream_t stream) {
  const float* h_text     = (const float*)d_in[0];
  const float* conv1_w    = (const float*)d_in[1];
  const float* conv1_b    = (const float*)d_in[2];
  const float* ln1_g      = (const float*)d_in[3];
  const float* ln1_b      = (const float*)d_in[4];
  const float* conv2_w    = (const float*)d_in[5];
  const float* conv2_b    = (const float*)d_in[6];
  const float* ln2_g      = (const float*)d_in[7];
  const float* ln2_b      = (const float*)d_in[8];
  const float* w_ih       = (const float*)d_in[9];
  const float* w_hh       = (const float*)d_in[10];
  const float* b_ih       = (const float*)d_in[11];
  const float* b_hh       = (const float*)d_in[12];
  const float* mdn_w_w    = (const float*)d_in[13];
  const float* mdn_w_b    = (const float*)d_in[14];
  const float* mdn_sig_w  = (const float*)d_in[15];
  const float* mdn_sig_b  = (const float*)d_in[16];
  const float* mdn_mu_w   = (const float*)d_in[17];
  const float* mdn_mu_b   = (const float*)d_in[18];
  float* out = (float*)d_out;

  char* ws = (char*)d_ws;
  size_t off = 0;
  auto take = [&](size_t bytes) {
    void* p = ws + off;
    off += (bytes + 255) & ~(size_t)255;
    return p;
  };
  ushort* xpad1  = (ushort*)take((size_t)BB * LPAD * DD * 2);
  ushort* xpad2  = (ushort*)take((size_t)BB * LPAD * DD * 2);
  ushort* wpack1 = (ushort*)take((size_t)DD * DD * 9 * 2);
  ushort* wpack2 = (ushort*)take((size_t)DD * DD * 9 * 2);
  float*  ybuf   = (float*) take((size_t)BB * LL * DD * 4);
  ushort* x2     = (ushort*)take((size_t)BB * LL * DD * 2);
  ushort* wihx   = (ushort*)take((size_t)3 * DD2 * DD * 2);
  ushort* gix    = (ushort*)take((size_t)BB * LL * 3 * DD2 * 2);   // packed layout
  ushort* Wp     = (ushort*)take((size_t)64 * 6 * GRU_KSTEPS * 64 * 8 * 2);
  ushort* hseq   = (ushort*)take((size_t)BB * LL * DD2 * 2);
  ushort* mdnmu  = (ushort*)take((size_t)KMIX * DD2 * DD2 * 2);
  ushort* mdnsg  = (ushort*)take((size_t)KMIX * DD2 * DD2 * 2);
  ushort* hbuf   = (ushort*)take((size_t)512 * 16384 * 2);   // 512 write-once frag buffers
  unsigned* flags = (unsigned*)take(64 * 16 * 4);            // 64 flags, 64B-padded lines

  const long sigma_off = (long)BB * LL * KMIX;                    // 65536
  const long mu_off    = sigma_off + (long)BB * LL * KMIX * DD2;  // 67174400

  // --- prep / packing ---
  k_fill_xpad<<<2048, 256, 0, stream>>>(h_text, xpad1);
  k_zero_bf16<<<2048, 256, 0, stream>>>(xpad2, (long)BB * LPAD * DD);
  k_pack_convw<<<2048, 256, 0, stream>>>(conv1_w, wpack1);
  k_pack_convw<<<2048, 256, 0, stream>>>(conv2_w, wpack2);
  k_pack_wihx<<<2048, 256, 0, stream>>>(w_ih, wihx);
  k_pack_gru<<<2048, 256, 0, stream>>>(w_ih, w_hh, b_hh, Wp);
  k_pack_bf16<<<2048, 256, 0, stream>>>(mdn_mu_w, mdnmu, (long)KMIX * DD2 * DD2);
  k_pack_bf16<<<2048, 256, 0, stream>>>(mdn_sig_w, mdnsg, (long)KMIX * DD2 * DD2);
  k_init_hbuf<<<64, 256, 0, stream>>>(hbuf, flags);

  // --- conv block 1: y = conv(xpad1) + b ; LN+ReLU -> xpad2 ---
  gemm128<0, 1><<<dim3(4, 64), 256, 0, stream>>>(xpad1, DD, DD, wpack1, DD, (long)DD * DD, 9, DD,
                                                 ybuf, DD, conv1_b);
  ln_relu<1><<<BB * LL, 256, 0, stream>>>(ybuf, ln1_g, ln1_b, xpad2);

  // --- conv block 2 -> x2 (GRU input, plain bf16 [8192,512]) ---
  gemm128<0, 1><<<dim3(4, 64), 256, 0, stream>>>(xpad2, DD, DD, wpack2, DD, (long)DD * DD, 9, DD,
                                                 ybuf, DD, conv2_b);
  ln_relu<0><<<BB * LL, 256, 0, stream>>>(ybuf, ln2_g, ln2_b, x2);

  // --- gi_x = x2 @ w_ih[:, :512]^T + b_ih -> PACKED gix layout (MODE=4) ---
  gemm128<4, 0><<<dim3(24, 64), 256, 0, stream>>>(x2, DD, 0, wihx, DD, 0, 1, DD,
                                                  gix, 3 * DD2, b_ih);

  // --- persistent GRU scan (8 waves, all weights register-resident) ---
  gru_scan<<<64, 512, 0, stream>>>(Wp, gix, b_hh, hbuf, hseq, flags);

  // --- MDN heads ---
  gemm128<3, 0><<<dim3(64, 64), 256, 0, stream>>>(hseq, DD2, 0, mdnsg, DD2, 0, 1, DD2,
                                                  out + sigma_off, KMIX * DD2, mdn_sig_b);
  gemm128<2, 0><<<dim3(64, 64), 256, 0, stream>>>(hseq, DD2, 0, mdnmu, DD2, 0, 1, DD2,
                                                  out + mu_off, KMIX * DD2, mdn_mu_b);
  w_head<<<BB * LL / 4, 256, 0, stream>>>(hseq, mdn_w_w, mdn_w_b, out);
}